// Round 1
// baseline (218.711 us; speedup 1.0000x reference)
//
#include <hip/hip_runtime.h>

static constexpr int N = 4096;
static constexpr int D = 8192;
static constexpr int BLOCK = 256;

// exp(x^2/10) and exp(a/10); fast-math intrinsics (threshold is 2% of |out|)

__global__ __launch_bounds__(BLOCK) void supcon_kernel(
    const float* __restrict__ emb,
    const int* __restrict__ labels,
    float* __restrict__ out)
{
    __shared__ int s_lab[N];          // 16 KB
    __shared__ float s_red[3][4];
    __shared__ int s_cnt[4];

    const int row = blockIdx.x;
    const int tid = threadIdx.x;

    // Stage labels to LDS, coalesced int4
    for (int k = tid; k < N / 4; k += BLOCK)
        reinterpret_cast<int4*>(s_lab)[k] = reinterpret_cast<const int4*>(labels)[k];
    __syncthreads();

    const int lab_i = s_lab[row];
    const float* rowp = emb + (size_t)row * D;

    float denom = 0.f, ssum = 0.f, diag = 0.f;
    int cnt = 0;

    // j in [0, N): denom + masked B-sum + count + diagonal
    for (int j0 = tid * 4; j0 < N; j0 += BLOCK * 4) {
        float4 x = *reinterpret_cast<const float4*>(rowp + j0);
        int4 lj = reinterpret_cast<const int4*>(s_lab)[j0 >> 2];  // ds_read_b128, conflict-free
        float xs[4] = {x.x, x.y, x.z, x.w};
        int   ls[4] = {lj.x, lj.y, lj.z, lj.w};
        #pragma unroll
        for (int k = 0; k < 4; ++k) {
            float a = __expf(xs[k] * xs[k] * 0.1f);
            denom += a;
            int j = j0 + k;
            float b = __expf(a * 0.1f);               // compute unconditionally: no divergence
            bool match = (ls[k] == lab_i) && (j != row);
            ssum += match ? b : 0.f;
            cnt  += match ? 1 : 0;
            if (j == row) diag = a;                    // exactly one thread/block takes this
        }
    }

    // j in [N, D): denom only
    for (int j0 = N + tid * 4; j0 < D; j0 += BLOCK * 4) {
        float4 x = *reinterpret_cast<const float4*>(rowp + j0);
        denom += __expf(x.x * x.x * 0.1f);
        denom += __expf(x.y * x.y * 0.1f);
        denom += __expf(x.z * x.z * 0.1f);
        denom += __expf(x.w * x.w * 0.1f);
    }

    // wave-64 shuffle reduction
    float fcnt = (float)cnt;  // max 4095, exact in fp32
    #pragma unroll
    for (int off = 32; off > 0; off >>= 1) {
        denom += __shfl_down(denom, off);
        ssum  += __shfl_down(ssum,  off);
        diag  += __shfl_down(diag,  off);
        fcnt  += __shfl_down(fcnt,  off);
    }
    const int wave = tid >> 6;
    const int lane = tid & 63;
    if (lane == 0) {
        s_red[0][wave] = denom;
        s_red[1][wave] = ssum;
        s_red[2][wave] = diag;
        s_cnt[wave]    = (int)fcnt;
    }
    __syncthreads();
    if (tid == 0) {
        float dn = 0.f, sv = 0.f, dg = 0.f; int c = 0;
        #pragma unroll
        for (int w = 0; w < 4; ++w) {
            dn += s_red[0][w]; sv += s_red[1][w]; dg += s_red[2][w]; c += s_cnt[w];
        }
        dn -= dg;   // denom_i = sum_d A - A[i,i]
        float val = __logf(sv) - __logf(dn) - __logf((float)c);
        atomicAdd(out, val);
    }
}

extern "C" void kernel_launch(void* const* d_in, const int* in_sizes, int n_in,
                              void* d_out, int out_size, void* d_ws, size_t ws_size,
                              hipStream_t stream) {
    const float* emb   = (const float*)d_in[0];
    const int* labels  = (const int*)d_in[1];
    float* out         = (float*)d_out;

    // d_out is poisoned (0xAA) before timed replays; zero it on-stream
    hipMemsetAsync(out, 0, sizeof(float), stream);
    supcon_kernel<<<dim3(N), dim3(BLOCK), 0, stream>>>(emb, labels, out);
}

// Round 2
// 187.794 us; speedup vs baseline: 1.1646x; 1.1646x over previous
//
#include <hip/hip_runtime.h>

static constexpr int N = 4096;
static constexpr int D = 8192;
static constexpr int BLOCK = 256;
// per thread: D/4/BLOCK = 8 float4 of embeddings, N/4/BLOCK = 4 int4 of labels

__global__ __launch_bounds__(BLOCK) void supcon_rows(
    const float* __restrict__ emb,
    const int* __restrict__ labels,
    float* __restrict__ row_out)
{
    const int row = blockIdx.x;
    const int tid = threadIdx.x;
    const int lab_i = labels[row];                       // wave-uniform, s_load-able
    const float4* rowp = reinterpret_cast<const float4*>(emb + (size_t)row * D);
    const int4* labp = reinterpret_cast<const int4*>(labels);

    // Issue ALL global loads up front: 12 loads in flight per wave (max MLP).
    float4 v[8];
    #pragma unroll
    for (int it = 0; it < 8; ++it)
        v[it] = rowp[tid + it * BLOCK];
    int4 lj[4];
    #pragma unroll
    for (int it = 0; it < 4; ++it)
        lj[it] = labp[tid + it * BLOCK];

    float denom = 0.f, ssum = 0.f, diag = 0.f, fcnt = 0.f;

    // First half: j in [0, N) -> denom + masked B-sum + count + diagonal
    #pragma unroll
    for (int it = 0; it < 4; ++it) {
        const int j0 = (tid + it * BLOCK) * 4;
        float xs[4] = {v[it].x, v[it].y, v[it].z, v[it].w};
        int   ls[4] = {lj[it].x, lj[it].y, lj[it].z, lj[it].w};
        #pragma unroll
        for (int k = 0; k < 4; ++k) {
            float a = __expf(xs[k] * xs[k] * 0.1f);
            denom += a;
            float b = __expf(a * 0.1f);                  // unconditional: no divergence
            bool match = (ls[k] == lab_i) && (j0 + k != row);
            ssum += match ? b : 0.f;
            fcnt += match ? 1.f : 0.f;
            diag += (j0 + k == row) ? a : 0.f;           // exactly one lane/block
        }
    }
    // Second half: j in [N, D) -> denom only
    #pragma unroll
    for (int it = 4; it < 8; ++it) {
        float xs[4] = {v[it].x, v[it].y, v[it].z, v[it].w};
        #pragma unroll
        for (int k = 0; k < 4; ++k)
            denom += __expf(xs[k] * xs[k] * 0.1f);
    }

    // wave-64 shuffle reduction
    #pragma unroll
    for (int off = 32; off > 0; off >>= 1) {
        denom += __shfl_down(denom, off);
        ssum  += __shfl_down(ssum,  off);
        diag  += __shfl_down(diag,  off);
        fcnt  += __shfl_down(fcnt,  off);
    }

    __shared__ float s_red[4][4];
    const int wave = tid >> 6;
    if ((tid & 63) == 0) {
        s_red[0][wave] = denom;
        s_red[1][wave] = ssum;
        s_red[2][wave] = diag;
        s_red[3][wave] = fcnt;
    }
    __syncthreads();
    if (tid == 0) {
        float dn = 0.f, sv = 0.f, dg = 0.f, c = 0.f;
        #pragma unroll
        for (int w = 0; w < 4; ++w) {
            dn += s_red[0][w]; sv += s_red[1][w]; dg += s_red[2][w]; c += s_red[3][w];
        }
        dn -= dg;   // denom_i = sum_d A[i,d] - A[i,i]
        row_out[row] = __logf(sv) - __logf(dn) - __logf(c);
    }
}

// 4096 row values -> scalar, one block of 1024 threads
__global__ __launch_bounds__(1024) void reduce_rows(
    const float* __restrict__ row_vals, float* __restrict__ out)
{
    const int tid = threadIdx.x;
    float4 x = reinterpret_cast<const float4*>(row_vals)[tid];
    float s = x.x + x.y + x.z + x.w;
    #pragma unroll
    for (int off = 32; off > 0; off >>= 1)
        s += __shfl_down(s, off);
    __shared__ float sb[16];
    if ((tid & 63) == 0) sb[tid >> 6] = s;
    __syncthreads();
    if (tid == 0) {
        float t = 0.f;
        #pragma unroll
        for (int w = 0; w < 16; ++w) t += sb[w];
        *out = t;
    }
}

extern "C" void kernel_launch(void* const* d_in, const int* in_sizes, int n_in,
                              void* d_out, int out_size, void* d_ws, size_t ws_size,
                              hipStream_t stream) {
    const float* emb  = (const float*)d_in[0];
    const int* labels = (const int*)d_in[1];
    float* out        = (float*)d_out;
    float* row_vals   = (float*)d_ws;   // 4096 floats = 16 KB scratch

    supcon_rows<<<dim3(N), dim3(BLOCK), 0, stream>>>(emb, labels, row_vals);
    reduce_rows<<<dim3(1), dim3(1024), 0, stream>>>(row_vals, out);
}